// Round 4
// baseline (3149.016 us; speedup 1.0000x reference)
//
#include <hip/hip_runtime.h>

#define N_NODES 50000
#define N_EDGES 800000
#define D 128
#define ED 64
#define NLAYERS 3

#define NB 16      // dst nodes per block in edge kernel (50000/16 = 3125 exact)
#define ET 128     // edge tile size
#define APAD 132   // sA row stride (floats)

// ---------------- prep kernels (build dst-sorted CSR each call) ----------------

__global__ void hist_kernel(const int* __restrict__ dst, int* __restrict__ deg) {
    int e = blockIdx.x * blockDim.x + threadIdx.x;
    if (e < N_EDGES) atomicAdd(&deg[dst[e]], 1);
}

__global__ void scan_kernel(int* __restrict__ deg_cursor, int* __restrict__ row_start) {
    __shared__ int part[1024];
    const int t = threadIdx.x;
    const int CH = (N_NODES + 1023) / 1024;  // 49
    int a = t * CH;
    int b = min(a + CH, N_NODES);
    int s = 0;
    for (int i = a; i < b; ++i) s += deg_cursor[i];
    part[t] = s;
    __syncthreads();
    for (int off = 1; off < 1024; off <<= 1) {
        int v = (t >= off) ? part[t - off] : 0;
        __syncthreads();
        part[t] += v;
        __syncthreads();
    }
    int base = (t == 0) ? 0 : part[t - 1];
    for (int i = a; i < b; ++i) {
        int d = deg_cursor[i];
        row_start[i] = base;
        deg_cursor[i] = base;
        base += d;
    }
    if (t == 1023) row_start[N_NODES] = part[1023];
}

__global__ void scatter_kernel(const int* __restrict__ dst, int* __restrict__ cursor,
                               int* __restrict__ perm) {
    int e = blockIdx.x * blockDim.x + threadIdx.x;
    if (e < N_EDGES) {
        int pos = atomicAdd(&cursor[dst[e]], 1);
        perm[pos] = e;
    }
}

// physically reorder edge_attr/src/dst into dst-sorted order (once per call).
// 4 lanes per edge row (64 B each), streaming write.
__global__ void reorder_kernel(const float4* __restrict__ ea, const int* __restrict__ perm,
                               const int* __restrict__ src, const int* __restrict__ dst,
                               float4* __restrict__ ea_d, int* __restrict__ srcd,
                               int* __restrict__ dstd) {
    int idx = blockIdx.x * blockDim.x + threadIdx.x;
    int i = idx >> 2, q = idx & 3;
    if (i < N_EDGES) {
        int pe = perm[i];
        const float4* srow = ea + (size_t)pe * (ED / 4);
        float4* drow = ea_d + (size_t)i * (ED / 4);
        #pragma unroll
        for (int j = 0; j < 4; ++j) drow[q * 4 + j] = srow[q * 4 + j];
        if (q == 0) { srcd[i] = src[pe]; dstd[i] = dst[pe]; }
    }
}

// ---------------- fused edge kernel, software-pipelined, streaming-friendly ----------------
// 512 threads, 3 blocks/CU (LDS ~43 KB). We read from global (L1-resident).
// In DIRECT mode (permN==nullptr) eaA/srcA/dstA are already dst-sorted: all
// staging loads are sequential streams; only the x[src] gather is random.

__global__ __launch_bounds__(512, 6)
void edge_agg_kernel(const float* __restrict__ x,
                     const float* __restrict__ eaA,   // [E][ED] (reordered if direct)
                     const int* __restrict__ srcA,
                     const int* __restrict__ dstA,
                     const int* __restrict__ permN,   // nullptr => direct
                     const int* __restrict__ row_start,
                     const float* __restrict__ We,    // [ED][D]
                     const float* __restrict__ be,    // [D]
                     float* __restrict__ hpre)        // [N][D]
{
    __shared__ float sA[ED][APAD];      // 33.8 KB : edge tile transposed [k][edge]
    __shared__ float sAgg[NB][D];       // 8 KB
    __shared__ int   sSrc[ET];
    __shared__ int   sDloc[ET];

    const int t  = threadIdx.x;
    const int n0 = blockIdx.x * NB;

    const int ei   = t & 127;   // staging edge slot
    const int part = t >> 7;    // 0..3 (stages 16 consecutive k of its edge)

    float4 pa0 = make_float4(0,0,0,0), pa1 = pa0, pa2 = pa0, pa3 = pa0;
    int p_src = 0, p_dloc = -1;

    const int eStart = row_start[n0];
    const int eEnd   = row_start[n0 + NB];

#define ISSUE(tb_, cnt_) do {                                                 \
        if (ei < (cnt_)) {                                                    \
            int g = (tb_) + ei;                                               \
            int pe = permN ? permN[g] : g;                                    \
            if (part == 0) { p_src = srcA[pe]; p_dloc = dstA[pe] - n0; }      \
            const float4* row4 = (const float4*)&eaA[(size_t)pe * ED];        \
            pa0 = row4[part * 4 + 0]; pa1 = row4[part * 4 + 1];               \
            pa2 = row4[part * 4 + 2]; pa3 = row4[part * 4 + 3];               \
        } else if (part == 0) { p_dloc = -1; }                                \
    } while (0)

    ISSUE(eStart, min(ET, eEnd - eStart));

    // zero sAgg, init sSrc
    ((float4*)&sAgg[0][0])[t] = make_float4(0.f, 0.f, 0.f, 0.f);
    if (t < ET) sSrc[t] = 0;

    const int r0 = (t >> 5) * 8;     // 8 edges per thread (half-wave uniform)
    const int c0 = (t & 31) * 4;     // 4 cols per thread
    const float4 bias = *(const float4*)&be[c0];
    const float* Wc = We + c0;

    for (int tb = eStart; tb < eEnd; tb += ET) {
        __syncthreads();   // prior tile's sA readers done (1st iter: init done)

        // commit in-flight regs -> sA (transposed), write metadata
        {
            const int kb = part * 16;
            sA[kb +  0][ei] = pa0.x; sA[kb +  1][ei] = pa0.y;
            sA[kb +  2][ei] = pa0.z; sA[kb +  3][ei] = pa0.w;
            sA[kb +  4][ei] = pa1.x; sA[kb +  5][ei] = pa1.y;
            sA[kb +  6][ei] = pa1.z; sA[kb +  7][ei] = pa1.w;
            sA[kb +  8][ei] = pa2.x; sA[kb +  9][ei] = pa2.y;
            sA[kb + 10][ei] = pa2.z; sA[kb + 11][ei] = pa2.w;
            sA[kb + 12][ei] = pa3.x; sA[kb + 13][ei] = pa3.y;
            sA[kb + 14][ei] = pa3.z; sA[kb + 15][ei] = pa3.w;
            if (part == 0) { sSrc[ei] = p_src; sDloc[ei] = p_dloc; }
        }
        __syncthreads();   // sA / sSrc / sDloc ready

        // x[src] prefetch for this tile's epilogue (consumed after k-loop)
        float4 xr[8]; int dls[8];
        #pragma unroll
        for (int e = 0; e < 8; ++e) {
            dls[e] = sDloc[r0 + e];
            int sn = sSrc[r0 + e];
            xr[e] = *(const float4*)&x[(size_t)sn * D + c0];
        }

        // issue NEXT tile's staging loads (streaming in direct mode)
        int ntb = tb + ET;
        if (ntb < eEnd) { ISSUE(ntb, min(ET, eEnd - ntb)); }

        // k-loop: sA from LDS, We streamed from global (L1-resident)
        float acc[8][4];
        #pragma unroll
        for (int e = 0; e < 8; ++e)
            #pragma unroll
            for (int j = 0; j < 4; ++j) acc[e][j] = 0.f;

        #pragma unroll 4
        for (int k = 0; k < ED; ++k) {
            float4 b4 = *(const float4*)&Wc[(size_t)k * D];
            float4 a0 = *(const float4*)&sA[k][r0];
            float4 a1 = *(const float4*)&sA[k][r0 + 4];
            float av[8] = {a0.x, a0.y, a0.z, a0.w, a1.x, a1.y, a1.z, a1.w};
            float bv[4] = {b4.x, b4.y, b4.z, b4.w};
            #pragma unroll
            for (int e = 0; e < 8; ++e)
                #pragma unroll
                for (int j = 0; j < 4; ++j)
                    acc[e][j] = fmaf(av[e], bv[j], acc[e][j]);
        }

        // epilogue: msg = relu(x[src] + e + be), aggregate in LDS
        #pragma unroll
        for (int e = 0; e < 8; ++e) {
            if (dls[e] < 0) continue;
            float4 xv = xr[e];
            float m0 = fmaxf(acc[e][0] + bias.x + xv.x, 0.f);
            float m1 = fmaxf(acc[e][1] + bias.y + xv.y, 0.f);
            float m2 = fmaxf(acc[e][2] + bias.z + xv.z, 0.f);
            float m3 = fmaxf(acc[e][3] + bias.w + xv.w, 0.f);
            atomicAdd(&sAgg[dls[e]][c0 + 0], m0);
            atomicAdd(&sAgg[dls[e]][c0 + 1], m1);
            atomicAdd(&sAgg[dls[e]][c0 + 2], m2);
            atomicAdd(&sAgg[dls[e]][c0 + 3], m3);
        }
    }
    __syncthreads();

    // writeout: hpre = agg + x  (16 rows x 32 float4 = 512 = one per thread)
    {
        int row = t >> 5, col = t & 31;
        float4 xv = ((const float4*)&x[(size_t)(n0 + row) * D])[col];
        float4 av = ((const float4*)&sAgg[row][0])[col];
        av.x += xv.x; av.y += xv.y; av.z += xv.z; av.w += xv.w;
        ((float4*)&hpre[(size_t)(n0 + row) * D])[col] = av;
    }
#undef ISSUE
}

// ---------------- MLP GEMM: out = [relu](in @ W + b) ----------------

__global__ __launch_bounds__(256, 3)
void mlp_kernel(const float* __restrict__ in,   // [N][D]
                const float* __restrict__ W,    // [D][D]
                const float* __restrict__ bias, // [D]
                float* __restrict__ out,        // [N][D]
                int do_relu)
{
    __shared__ float sWh[64][D];     // 32 KB : W[k0+kl][c]
    __shared__ float sIn[64][68];    // 17.4 KB : input tile transposed [kl][row]

    const int t  = threadIdx.x;
    const int n0 = blockIdx.x * 64;
    const int r0 = (t >> 5) * 8;
    const int c0 = (t & 31) * 4;

    float acc[8][4];
    #pragma unroll
    for (int e = 0; e < 8; ++e)
        #pragma unroll
        for (int j = 0; j < 4; ++j) acc[e][j] = 0.f;

    for (int k0 = 0; k0 < D; k0 += 64) {
        __syncthreads();
        {
            const float4* w4 = (const float4*)W;
            #pragma unroll
            for (int i = 0; i < 8; ++i) {
                int idx = t + i * 256;
                int kl = idx >> 5, c4 = idx & 31;
                *(float4*)&sWh[kl][c4 * 4] = w4[(size_t)(k0 + kl) * 32 + c4];
            }
        }
        {
            int r = t & 63, prt = t >> 6;
            int gr = n0 + r;
            #pragma unroll
            for (int q = 0; q < 4; ++q) {
                float4 v = make_float4(0.f, 0.f, 0.f, 0.f);
                if (gr < N_NODES) v = ((const float4*)&in[(size_t)gr * D])[(k0 >> 2) + prt * 4 + q];
                int kl = prt * 16 + q * 4;
                sIn[kl + 0][r] = v.x;
                sIn[kl + 1][r] = v.y;
                sIn[kl + 2][r] = v.z;
                sIn[kl + 3][r] = v.w;
            }
        }
        __syncthreads();

        #pragma unroll 8
        for (int kl = 0; kl < 64; ++kl) {
            float4 b4 = *(const float4*)&sWh[kl][c0];
            float4 a0 = *(const float4*)&sIn[kl][r0];
            float4 a1 = *(const float4*)&sIn[kl][r0 + 4];
            float av[8] = {a0.x, a0.y, a0.z, a0.w, a1.x, a1.y, a1.z, a1.w};
            float bv[4] = {b4.x, b4.y, b4.z, b4.w};
            #pragma unroll
            for (int e = 0; e < 8; ++e)
                #pragma unroll
                for (int j = 0; j < 4; ++j)
                    acc[e][j] = fmaf(av[e], bv[j], acc[e][j]);
        }
    }

    float4 bb = *(const float4*)&bias[c0];
    #pragma unroll
    for (int e = 0; e < 8; ++e) {
        int gr = n0 + r0 + e;
        if (gr < N_NODES) {
            float4 o;
            o.x = acc[e][0] + bb.x;
            o.y = acc[e][1] + bb.y;
            o.z = acc[e][2] + bb.z;
            o.w = acc[e][3] + bb.w;
            if (do_relu) {
                o.x = fmaxf(o.x, 0.f); o.y = fmaxf(o.y, 0.f);
                o.z = fmaxf(o.z, 0.f); o.w = fmaxf(o.w, 0.f);
            }
            *(float4*)&out[(size_t)gr * D + c0] = o;
        }
    }
}

// ---------------- host ----------------

extern "C" void kernel_launch(void* const* d_in, const int* in_sizes, int n_in,
                              void* d_out, int out_size, void* d_ws, size_t ws_size,
                              hipStream_t stream) {
    const float* x  = (const float*)d_in[0];
    const int*   ei = (const int*)d_in[1];
    const float* ea = (const float*)d_in[2];
    const float* We = (const float*)d_in[3];
    const float* be = (const float*)d_in[4];
    const float* W1 = (const float*)d_in[5];
    const float* b1 = (const float*)d_in[6];
    const float* W2 = (const float*)d_in[7];
    const float* b2 = (const float*)d_in[8];
    float* out = (float*)d_out;

    const int* src = ei;
    const int* dst = ei + N_EDGES;

    char* ws = (char*)d_ws;
    size_t off = 0;
    auto alloc = [&](size_t bytes) -> char* {
        char* p = ws + off;
        off = (off + bytes + 255) & ~(size_t)255;
        return p;
    };
    float* P         = (float*)alloc((size_t)N_NODES * D * sizeof(float));
    float* T         = (float*)alloc((size_t)N_NODES * D * sizeof(float));
    float* H         = (float*)alloc((size_t)N_NODES * D * sizeof(float));
    int*   perm      = (int*)alloc((size_t)N_EDGES * sizeof(int));
    int*   row_start = (int*)alloc((size_t)(N_NODES + 1) * sizeof(int));
    int*   cursor    = (int*)alloc((size_t)N_NODES * sizeof(int));
    // big reordered buffers last; fall back to indirect mode if ws too small
    size_t off_small = off;
    int*   srcd = (int*)alloc((size_t)N_EDGES * sizeof(int));
    int*   dstd = (int*)alloc((size_t)N_EDGES * sizeof(int));
    float* ea_d = (float*)alloc((size_t)N_EDGES * ED * sizeof(float));
    const bool direct = (off <= ws_size);
    (void)in_sizes; (void)n_in; (void)out_size; (void)off_small;

    // build dst-sorted CSR (deterministic structure; runs every call)
    hipMemsetAsync(cursor, 0, N_NODES * sizeof(int), stream);
    hist_kernel<<<(N_EDGES + 255) / 256, 256, 0, stream>>>(dst, cursor);
    scan_kernel<<<1, 1024, 0, stream>>>(cursor, row_start);
    scatter_kernel<<<(N_EDGES + 255) / 256, 256, 0, stream>>>(dst, cursor, perm);

    const float* eaA = ea;
    const int *srcA = src, *dstA = dst, *permN = perm;
    if (direct) {
        reorder_kernel<<<(N_EDGES * 4 + 255) / 256, 256, 0, stream>>>(
            (const float4*)ea, perm, src, dst, (float4*)ea_d, srcd, dstd);
        eaA = ea_d; srcA = srcd; dstA = dstd; permN = nullptr;
    }

    const float* X = x;
    const int egrid = N_NODES / NB;            // 3125
    const int mgrid = (N_NODES + 63) / 64;     // 782
    for (int l = 0; l < NLAYERS; ++l) {
        edge_agg_kernel<<<egrid, 512, 0, stream>>>(X, eaA, srcA, dstA, permN, row_start,
            We + (size_t)l * ED * D, be + (size_t)l * D, P);
        mlp_kernel<<<mgrid, 256, 0, stream>>>(P, W1 + (size_t)l * D * D, b1 + (size_t)l * D, T, 1);
        float* ob = (l < NLAYERS - 1) ? H : out;
        mlp_kernel<<<mgrid, 256, 0, stream>>>(T, W2 + (size_t)l * D * D, b2 + (size_t)l * D, ob,
                                              (l < NLAYERS - 1) ? 1 : 0);
        X = H;
    }
}

// Round 5
// 2348.020 us; speedup vs baseline: 1.3411x; 1.3411x over previous
//
#include <hip/hip_runtime.h>

#define N_NODES 50000
#define N_EDGES 800000
#define D 128
#define ED 64
#define NLAYERS 3

// ---------------- prep kernels (build dst-sorted CSR each call) ----------------

__global__ void hist_kernel(const int* __restrict__ dst, int* __restrict__ deg) {
    int e = blockIdx.x * blockDim.x + threadIdx.x;
    if (e < N_EDGES) atomicAdd(&deg[dst[e]], 1);
}

__global__ void scan_kernel(int* __restrict__ deg_cursor, int* __restrict__ row_start) {
    __shared__ int part[1024];
    const int t = threadIdx.x;
    const int CH = (N_NODES + 1023) / 1024;  // 49
    int a = t * CH;
    int b = min(a + CH, N_NODES);
    int s = 0;
    for (int i = a; i < b; ++i) s += deg_cursor[i];
    part[t] = s;
    __syncthreads();
    for (int off = 1; off < 1024; off <<= 1) {
        int v = (t >= off) ? part[t - off] : 0;
        __syncthreads();
        part[t] += v;
        __syncthreads();
    }
    int base = (t == 0) ? 0 : part[t - 1];
    for (int i = a; i < b; ++i) {
        int d = deg_cursor[i];
        row_start[i] = base;
        deg_cursor[i] = base;
        base += d;
    }
    if (t == 1023) row_start[N_NODES] = part[1023];
}

__global__ void scatter_kernel(const int* __restrict__ dst, int* __restrict__ cursor,
                               int* __restrict__ perm) {
    int e = blockIdx.x * blockDim.x + threadIdx.x;
    if (e < N_EDGES) {
        int pos = atomicAdd(&cursor[dst[e]], 1);
        perm[pos] = e;
    }
}

// physically reorder edge_attr/src into dst-sorted order (once per call).
__global__ void reorder_kernel(const float4* __restrict__ ea, const int* __restrict__ perm,
                               const int* __restrict__ src,
                               float4* __restrict__ ea_d, int* __restrict__ srcd) {
    int idx = blockIdx.x * blockDim.x + threadIdx.x;
    int i = idx >> 2, q = idx & 3;
    if (i < N_EDGES) {
        int pe = perm[i];
        const float4* srow = ea + (size_t)pe * (ED / 4);
        float4* drow = ea_d + (size_t)i * (ED / 4);
        #pragma unroll
        for (int j = 0; j < 4; ++j) drow[q * 4 + j] = srow[q * 4 + j];
        if (q == 0) srcd[i] = src[pe];
    }
}

// ---------------- edge pass: per-wave segmented streaming, no LDS / barriers / atomics ----------------
// Each wave owns a contiguous dst-sorted edge range snapped to node boundaries
// (node n owned by the wave whose target range contains row_start[n]).
// Lane owns 2 output cols; We[:,c0:c0+2] held in 128 VGPRs; ea row read via
// wave-uniform float4 loads (broadcast); x[src] is the only gather.

__global__ __launch_bounds__(256, 3)
void edge_agg_kernel(const float* __restrict__ x,
                     const float* __restrict__ eaA,   // [E][ED] (dst-sorted if direct)
                     const int* __restrict__ srcA,
                     const int* __restrict__ permN,   // nullptr => direct (sorted) mode
                     const int* __restrict__ row_start,
                     const float* __restrict__ We,    // [ED][D]
                     const float* __restrict__ be,    // [D]
                     float* __restrict__ hpre,        // [N][D]
                     int nwaves, int epw)
{
    const int t    = threadIdx.x;
    const int lane = t & 63;
    const int wid  = (blockIdx.x * 256 + t) >> 6;
    if (wid >= nwaves) return;
    const int c0 = lane * 2;

    // preload We columns c0,c0+1 (128 VGPRs, statically indexed after unroll)
    float2 wk[64];
    #pragma unroll
    for (int k = 0; k < 64; ++k)
        wk[k] = *(const float2*)&We[k * D + c0];
    const float2 be2 = *(const float2*)&be[c0];

    // node range: lower_bound(row_start, target) over [0, N_NODES)
    int lo_t = min(wid * epw, N_EDGES);
    int hi_t = min((wid + 1) * epw, N_EDGES);
    int n_lo, n_hi;
    {
        int a = 0, b = N_NODES;
        while (a < b) { int m = (a + b) >> 1; if (row_start[m] < lo_t) a = m + 1; else b = m; }
        n_lo = a;
    }
    if (wid == nwaves - 1) {
        n_hi = N_NODES;  // last wave sweeps trailing (incl. degree-0 tail) nodes
    } else {
        int a = 0, b = N_NODES;
        while (a < b) { int m = (a + b) >> 1; if (row_start[m] < hi_t) a = m + 1; else b = m; }
        n_hi = a;
    }

    for (int n = n_lo; n < n_hi; ++n) {
        float2 acc = *(const float2*)&x[(size_t)n * D + c0];   // (1+eps)*x, eps=0
        const int ebeg = row_start[n], eend = row_start[n + 1];
        for (int e = ebeg; e < eend; ++e) {
            const int pe = permN ? permN[e] : e;
            const int sn = srcA[pe];
            const float2 xs = *(const float2*)&x[(size_t)sn * D + c0];
            const float4* __restrict__ ar = (const float4*)&eaA[(size_t)pe * ED];
            float s0 = 0.f, s1 = 0.f, s2 = 0.f, s3 = 0.f;
            #pragma unroll
            for (int kq = 0; kq < 16; kq += 2) {
                float4 a0 = ar[kq];
                float4 a1 = ar[kq + 1];
                s0 = fmaf(a0.x, wk[4*kq+0].x, s0); s1 = fmaf(a0.x, wk[4*kq+0].y, s1);
                s0 = fmaf(a0.y, wk[4*kq+1].x, s0); s1 = fmaf(a0.y, wk[4*kq+1].y, s1);
                s0 = fmaf(a0.z, wk[4*kq+2].x, s0); s1 = fmaf(a0.z, wk[4*kq+2].y, s1);
                s0 = fmaf(a0.w, wk[4*kq+3].x, s0); s1 = fmaf(a0.w, wk[4*kq+3].y, s1);
                s2 = fmaf(a1.x, wk[4*kq+4].x, s2); s3 = fmaf(a1.x, wk[4*kq+4].y, s3);
                s2 = fmaf(a1.y, wk[4*kq+5].x, s2); s3 = fmaf(a1.y, wk[4*kq+5].y, s3);
                s2 = fmaf(a1.z, wk[4*kq+6].x, s2); s3 = fmaf(a1.z, wk[4*kq+6].y, s3);
                s2 = fmaf(a1.w, wk[4*kq+7].x, s2); s3 = fmaf(a1.w, wk[4*kq+7].y, s3);
            }
            float m0 = fmaxf(xs.x + s0 + s2 + be2.x, 0.f);
            float m1 = fmaxf(xs.y + s1 + s3 + be2.y, 0.f);
            acc.x += m0;
            acc.y += m1;
        }
        *(float2*)&hpre[(size_t)n * D + c0] = acc;
    }
}

// ---------------- MLP GEMM: out = [relu](in @ W + b) ----------------

__global__ __launch_bounds__(256, 3)
void mlp_kernel(const float* __restrict__ in,   // [N][D]
                const float* __restrict__ W,    // [D][D]
                const float* __restrict__ bias, // [D]
                float* __restrict__ out,        // [N][D]
                int do_relu)
{
    __shared__ float sWh[64][D];     // 32 KB : W[k0+kl][c]
    __shared__ float sIn[64][68];    // 17.4 KB : input tile transposed [kl][row]

    const int t  = threadIdx.x;
    const int n0 = blockIdx.x * 64;
    const int r0 = (t >> 5) * 8;
    const int c0 = (t & 31) * 4;

    float acc[8][4];
    #pragma unroll
    for (int e = 0; e < 8; ++e)
        #pragma unroll
        for (int j = 0; j < 4; ++j) acc[e][j] = 0.f;

    for (int k0 = 0; k0 < D; k0 += 64) {
        __syncthreads();
        {
            const float4* w4 = (const float4*)W;
            #pragma unroll
            for (int i = 0; i < 8; ++i) {
                int idx = t + i * 256;
                int kl = idx >> 5, c4 = idx & 31;
                *(float4*)&sWh[kl][c4 * 4] = w4[(size_t)(k0 + kl) * 32 + c4];
            }
        }
        {
            int r = t & 63, prt = t >> 6;
            int gr = n0 + r;
            #pragma unroll
            for (int q = 0; q < 4; ++q) {
                float4 v = make_float4(0.f, 0.f, 0.f, 0.f);
                if (gr < N_NODES) v = ((const float4*)&in[(size_t)gr * D])[(k0 >> 2) + prt * 4 + q];
                int kl = prt * 16 + q * 4;
                sIn[kl + 0][r] = v.x;
                sIn[kl + 1][r] = v.y;
                sIn[kl + 2][r] = v.z;
                sIn[kl + 3][r] = v.w;
            }
        }
        __syncthreads();

        #pragma unroll 8
        for (int kl = 0; kl < 64; ++kl) {
            float4 b4 = *(const float4*)&sWh[kl][c0];
            float4 a0 = *(const float4*)&sIn[kl][r0];
            float4 a1 = *(const float4*)&sIn[kl][r0 + 4];
            float av[8] = {a0.x, a0.y, a0.z, a0.w, a1.x, a1.y, a1.z, a1.w};
            float bv[4] = {b4.x, b4.y, b4.z, b4.w};
            #pragma unroll
            for (int e = 0; e < 8; ++e)
                #pragma unroll
                for (int j = 0; j < 4; ++j)
                    acc[e][j] = fmaf(av[e], bv[j], acc[e][j]);
        }
    }

    float4 bb = *(const float4*)&bias[c0];
    #pragma unroll
    for (int e = 0; e < 8; ++e) {
        int gr = n0 + r0 + e;
        if (gr < N_NODES) {
            float4 o;
            o.x = acc[e][0] + bb.x;
            o.y = acc[e][1] + bb.y;
            o.z = acc[e][2] + bb.z;
            o.w = acc[e][3] + bb.w;
            if (do_relu) {
                o.x = fmaxf(o.x, 0.f); o.y = fmaxf(o.y, 0.f);
                o.z = fmaxf(o.z, 0.f); o.w = fmaxf(o.w, 0.f);
            }
            *(float4*)&out[(size_t)gr * D + c0] = o;
        }
    }
}

// ---------------- host ----------------

extern "C" void kernel_launch(void* const* d_in, const int* in_sizes, int n_in,
                              void* d_out, int out_size, void* d_ws, size_t ws_size,
                              hipStream_t stream) {
    const float* x  = (const float*)d_in[0];
    const int*   ei = (const int*)d_in[1];
    const float* ea = (const float*)d_in[2];
    const float* We = (const float*)d_in[3];
    const float* be = (const float*)d_in[4];
    const float* W1 = (const float*)d_in[5];
    const float* b1 = (const float*)d_in[6];
    const float* W2 = (const float*)d_in[7];
    const float* b2 = (const float*)d_in[8];
    float* out = (float*)d_out;

    const int* src = ei;
    const int* dst = ei + N_EDGES;

    char* ws = (char*)d_ws;
    size_t off = 0;
    auto alloc = [&](size_t bytes) -> char* {
        char* p = ws + off;
        off = (off + bytes + 255) & ~(size_t)255;
        return p;
    };
    float* P         = (float*)alloc((size_t)N_NODES * D * sizeof(float));
    float* T         = (float*)alloc((size_t)N_NODES * D * sizeof(float));
    float* H         = (float*)alloc((size_t)N_NODES * D * sizeof(float));
    int*   perm      = (int*)alloc((size_t)N_EDGES * sizeof(int));
    int*   row_start = (int*)alloc((size_t)(N_NODES + 1) * sizeof(int));
    int*   cursor    = (int*)alloc((size_t)N_NODES * sizeof(int));
    // big reordered buffers last; fall back to indirect mode if ws too small
    int*   srcd = (int*)alloc((size_t)N_EDGES * sizeof(int));
    float* ea_d = (float*)alloc((size_t)N_EDGES * ED * sizeof(float));
    const bool direct = (off <= ws_size);
    (void)in_sizes; (void)n_in; (void)out_size;

    // build dst-sorted CSR (deterministic structure; runs every call)
    hipMemsetAsync(cursor, 0, N_NODES * sizeof(int), stream);
    hist_kernel<<<(N_EDGES + 255) / 256, 256, 0, stream>>>(dst, cursor);
    scan_kernel<<<1, 1024, 0, stream>>>(cursor, row_start);
    scatter_kernel<<<(N_EDGES + 255) / 256, 256, 0, stream>>>(dst, cursor, perm);

    const float* eaA = ea;
    const int *srcA = src, *permN = perm;
    if (direct) {
        reorder_kernel<<<(N_EDGES * 4 + 255) / 256, 256, 0, stream>>>(
            (const float4*)ea, perm, src, (float4*)ea_d, srcd);
        eaA = ea_d; srcA = srcd; permN = nullptr;
    }

    // one wave per edge-range; 3072 waves == exactly full residency at 3 waves/SIMD
    const int nwaves = 3072;
    const int eblocks = nwaves / 4;            // 256 threads = 4 waves per block
    const int epw = (N_EDGES + nwaves - 1) / nwaves;   // 261
    const int mgrid = (N_NODES + 63) / 64;     // 782

    const float* X = x;
    for (int l = 0; l < NLAYERS; ++l) {
        edge_agg_kernel<<<eblocks, 256, 0, stream>>>(X, eaA, srcA, permN, row_start,
            We + (size_t)l * ED * D, be + (size_t)l * D, P, nwaves, epw);
        mlp_kernel<<<mgrid, 256, 0, stream>>>(P, W1 + (size_t)l * D * D, b1 + (size_t)l * D, T, 1);
        float* ob = (l < NLAYERS - 1) ? H : out;
        mlp_kernel<<<mgrid, 256, 0, stream>>>(T, W2 + (size_t)l * D * D, b2 + (size_t)l * D, ob,
                                              (l < NLAYERS - 1) ? 1 : 0);
        X = H;
    }
}